// Round 1
// baseline (689.332 us; speedup 1.0000x reference)
//
#include <hip/hip_runtime.h>
#include <math.h>
#include <stdint.h>

#define NQ 12
#define DIMK 256
#define NCTRL 25
#define TPB 256
#define TILE 64          // points per tile; 64 rows * 1KB = 64KB per buffer

// ---------------------------------------------------------------------------
// Design (this round):
//  * Persistent blocks: grid = min(ntiles,256), 1 block/CU (LDS-capped at
//    128KB+sC). Each block grid-strides over 64-point tiles.
//  * emb streamed via __builtin_amdgcn_global_load_lds width=16: each wave
//    instruction stages one full 1KB row (64 lanes x 16B contiguous) -> full
//    cacheline utilization, zero VGPR cost, deep async pipeline.
//  * Rows are WAVE-PRIVATE (wave w stages and consumes rows [16w,16w+16)),
//    so the double-buffered main loop needs no __syncthreads -- each wave
//    self-synchronizes with s_waitcnt vmcnt(0).
//  * 16 lanes per point: lane h owns k in {4h+64m+t}; W slice lives in 192
//    VGPRs (no per-tile W traffic at all). e-reads are 4x ds_read_b128 per
//    point, bank-balanced (16 distinct 16B chunks per instruction).
//  * Reductions over the 16-lane cluster are pure-VALU DPP (quad_perm,
//    row_ror:4/8) -- DS pipe stays free for the e-stream.
//  * Epilogue distributed: lane h evaluates spline q=h (h<12), DPP-sum of
//    a_q*phi_q, lane 0 stores.
// Predicted: memory-bound, ~85-105us kernel, ~5.5-6.2 TB/s fetch.
// ---------------------------------------------------------------------------

template<int CTRL>
__device__ __forceinline__ float dpp_red(float v) {
    int t = __builtin_amdgcn_mov_dpp(__float_as_int(v), CTRL, 0xF, 0xF, 1);
    return v + __int_as_float(t);
}

// Sum across the 16-lane DPP row. quad_perm(1,0,3,2)=0xB1, quad_perm(2,3,0,1)
// =0x4E give quad sums; row_ror:4 (0x124) then row_ror:8 (0x128) combine the
// four quad-uniform partials -> every lane holds the full 16-lane sum.
__device__ __forceinline__ float row16_sum(float v) {
    v = dpp_red<0xB1>(v);
    v = dpp_red<0x4E>(v);
    v = dpp_red<0x124>(v);
    v = dpp_red<0x128>(v);
    return v;
}

// Stage one 64-point tile's rows for this wave (rows [16w,16w+16)) into LDS.
// Each call: dst uniform per wave, 64 lanes deliver 16B each = 1KB row.
__device__ __forceinline__ void stage_tile(const float* __restrict__ emb,
                                           float* dstbase, int p0,
                                           int w, int lane, int nm1) {
    #pragma unroll
    for (int j = 0; j < 16; ++j) {
        const int row = (w << 4) + j;
        int grow = p0 + row;
        grow = grow > nm1 ? nm1 : grow;           // clamp: safe read, discarded
        const float* src = emb + (size_t)grow * DIMK + (lane << 2);
        float* dst = dstbase + row * DIMK;
        __builtin_amdgcn_global_load_lds(
            (const __attribute__((address_space(1))) void*)src,
            (__attribute__((address_space(3))) void*)dst,
            16, 0, 0);
    }
}

__global__ __launch_bounds__(TPB, 1) void kan_bspline_kernel(
    const float* __restrict__ emb,
    const float* __restrict__ W,
    const float* __restrict__ b_inner,
    const float* __restrict__ inner_scale,
    const float* __restrict__ coeffs,
    const float* __restrict__ a_out,
    const float* __restrict__ b_out,
    float* __restrict__ out,
    int n)
{
    __shared__ __align__(16) float sE[2 * TILE * DIMK];   // 128 KB, dbuf
    __shared__ float sC[NQ * NCTRL];                      // 1.2 KB

    const int tid  = threadIdx.x;
    const int w    = tid >> 6;       // wave 0..3
    const int lane = tid & 63;
    const int cl   = lane >> 4;      // 16-lane cluster 0..3
    const int h    = lane & 15;      // lane within cluster
    const int nm1  = n - 1;
    const int ntiles = (n + TILE - 1) / TILE;
    const int G = (int)gridDim.x;

    // stage coeffs once (only __syncthreads in the kernel)
    for (int i = tid; i < NQ * NCTRL; i += TPB) sC[i] = coeffs[i];
    __syncthreads();

    // W slice in registers: lane h owns k = 4h + 64m + t, all 12 q -> 192 VGPR
    float4 wq[NQ][4];
    #pragma unroll
    for (int q = 0; q < NQ; ++q)
        #pragma unroll
        for (int m = 0; m < 4; ++m)
            wq[q][m] = *(const float4*)(W + q * DIMK + (m << 6) + (h << 2));

    const float b_h = (h < NQ) ? b_inner[h] : 0.0f;
    const float a_h = (h < NQ) ? a_out[h]   : 0.0f;
    const float scale = inner_scale[0];
    const float bout  = b_out[0];

    const float hh  = 1.0f / 22.0f;
    const float i1h = 22.0f;
    const float i2h = 11.0f;
    const float i3h = 22.0f / 3.0f;

    int buf = 0;
    const int t0 = blockIdx.x;       // grid < ntiles guaranteed by launcher
    stage_tile(emb, sE, t0 * TILE, w, lane, nm1);
    asm volatile("s_waitcnt vmcnt(0)" ::: "memory");

    for (int t = t0; t < ntiles; t += G) {
        const int tn = t + G;
        if (tn < ntiles)
            stage_tile(emb, sE + ((buf ^ 1) * (TILE * DIMK)), tn * TILE, w, lane, nm1);

        // ---- compute tile t from sE[buf] (wave-private rows) ----
        const float* bp = sE + buf * (TILE * DIMK);
        const int p0 = t * TILE;

        #pragma unroll
        for (int s = 0; s < 4; ++s) {
            const int r = (w << 4) + (s << 2) + cl;   // row in [16w,16w+16)
            const float* ep = bp + r * DIMK + (h << 2);
            const float4 e0 = *(const float4*)(ep);
            const float4 e1 = *(const float4*)(ep + 64);
            const float4 e2 = *(const float4*)(ep + 128);
            const float4 e3 = *(const float4*)(ep + 192);

            float red[NQ];
            #pragma unroll
            for (int q = 0; q < NQ; ++q) {
                float acc;
                acc  = e0.x * wq[q][0].x;
                acc += e0.y * wq[q][0].y;
                acc += e0.z * wq[q][0].z;
                acc += e0.w * wq[q][0].w;
                acc += e1.x * wq[q][1].x;
                acc += e1.y * wq[q][1].y;
                acc += e1.z * wq[q][1].z;
                acc += e1.w * wq[q][1].w;
                acc += e2.x * wq[q][2].x;
                acc += e2.y * wq[q][2].y;
                acc += e2.z * wq[q][2].z;
                acc += e2.w * wq[q][2].w;
                acc += e3.x * wq[q][3].x;
                acc += e3.y * wq[q][3].y;
                acc += e3.z * wq[q][3].z;
                acc += e3.w * wq[q][3].w;
                red[q] = row16_sum(acc);     // all 16 lanes get full u[q]
            }

            // lane h picks u[h] via cndmask chain (no runtime array index)
            float uq = 0.0f;
            #pragma unroll
            for (int q = 0; q < NQ; ++q) uq = (h == q) ? red[q] : uq;

            // ---- epilogue: spline q=h (lanes h>=NQ contribute 0) ----
            const float uu = uq + b_h;
            const float sv = 0.5f * tanhf(scale * uu) + 0.5f;   // in [0,1]

            int iv = (int)(sv * 22.0f);
            iv = iv > 21 ? 21 : iv;
            iv = iv < 0 ? 0 : iv;
            const float fiv = (float)iv;

            const float l1 = sv - fiv * hh;
            const float l2 = sv - fmaxf(fiv - 1.0f, 0.0f) * hh;
            const float l3 = sv - fmaxf(fiv - 2.0f, 0.0f) * hh;
            const float r1 = fminf((fiv + 1.0f) * hh, 1.0f) - sv;
            const float r2 = fminf((fiv + 2.0f) * hh, 1.0f) - sv;
            const float r3 = fminf((fiv + 3.0f) * hh, 1.0f) - sv;

            const float inv_b = (iv >= 1) ? i2h : i1h;
            const float inv_c = (iv <= 20) ? i2h : i1h;
            const float inv_d = (iv >= 2) ? i3h : ((iv >= 1) ? i2h : i1h);
            const float inv_e = (iv >= 1 && iv <= 20) ? i3h : i2h;
            const float inv_f = (iv <= 19) ? i3h : ((iv <= 20) ? i2h : i1h);

            float tmp, saved;
            tmp = i1h;
            float N0v = r1 * tmp;
            float N1v = l1 * tmp;
            tmp   = N0v * inv_b;
            N0v   = r1 * tmp;
            saved = l2 * tmp;
            tmp   = N1v * inv_c;
            N1v   = saved + r2 * tmp;
            float N2v = l1 * tmp;
            tmp   = N0v * inv_d;
            N0v   = r1 * tmp;
            saved = l3 * tmp;
            tmp   = N1v * inv_e;
            N1v   = saved + r2 * tmp;
            saved = l2 * tmp;
            tmp   = N2v * inv_f;
            N2v   = saved + r3 * tmp;
            float N3v = l1 * tmp;

            const int qe = (h < NQ) ? h : 0;            // keep sC read in-bounds
            const float* cq = sC + qe * NCTRL + iv;
            const float phi = N0v * cq[0] + N1v * cq[1] + N2v * cq[2] + N3v * cq[3];

            float part = a_h * phi;                     // 0 for h>=NQ
            part = row16_sum(part);

            if (h == 0) {
                const int pidx = p0 + r;
                if (pidx < n) out[pidx] = part + bout;
            }
        }

        // next tile's rows (this wave's 16 loads) must have landed
        asm volatile("s_waitcnt vmcnt(0)" ::: "memory");
        buf ^= 1;
    }
}

extern "C" void kernel_launch(void* const* d_in, const int* in_sizes, int n_in,
                              void* d_out, int out_size, void* d_ws, size_t ws_size,
                              hipStream_t stream) {
    const float* emb         = (const float*)d_in[0];
    const float* W           = (const float*)d_in[1];
    const float* b_inner     = (const float*)d_in[2];
    const float* inner_scale = (const float*)d_in[3];
    const float* coeffs      = (const float*)d_in[4];
    const float* a_out       = (const float*)d_in[5];
    const float* b_out       = (const float*)d_in[6];
    float* out = (float*)d_out;

    const int n = in_sizes[0] / DIMK;
    const int ntiles = (n + TILE - 1) / TILE;
    int grid = ntiles < 256 ? ntiles : 256;   // persistent: 1 block per CU
    kan_bspline_kernel<<<grid, TPB, 0, stream>>>(
        emb, W, b_inner, inner_scale, coeffs, a_out, b_out, out, n);
}